// Round 4
// baseline (223.824 us; speedup 1.0000x reference)
//
#include <hip/hip_runtime.h>
#include <cstdint>
#include <cstddef>

#define B_ 4
#define N_ 16384
#define M_ 2048
#define C_ 64
#define S_ 32
#define J_ 67          // 3 + C
#define R2_ 0.04f
#define EPS_ 1e-5f
#define NBLK_ 512      // persistent grid: 2x residency margin (capacity >= 1024)
#define CPB_ 16        // centers per block (512*16 = 8192 = B*M)

// Device-scope grid barrier: monotonic counter per sync point, reset each
// call by hipMemsetAsync. Only tid 0 spins; release/acquire at agent scope
// handles cross-XCD L2 visibility (guide §6 G16).
__device__ __forceinline__ void gridsync(int* cnt, int target) {
    __syncthreads();                          // drains vmcnt: block's stores in L2
    if (threadIdx.x == 0) {
        __hip_atomic_fetch_add(cnt, 1, __ATOMIC_RELEASE, __HIP_MEMORY_SCOPE_AGENT);
        while (__hip_atomic_load(cnt, __ATOMIC_ACQUIRE, __HIP_MEMORY_SCOPE_AGENT) < target)
            __builtin_amdgcn_s_sleep(1);
    }
    __syncthreads();
    __threadfence();                          // invalidate caches for fresh reads
}

__global__ __launch_bounds__(256, 4) void k_fused(
        const float* __restrict__ pts, const float* __restrict__ ctr,
        const float* __restrict__ cfeat, const float* __restrict__ feat,
        const float* __restrict__ alpha, const float* __restrict__ beta,
        float* __restrict__ featT, float* __restrict__ bpart,
        int* __restrict__ syncc, float* __restrict__ out) {

    __shared__ float tile[64][65];            // transpose tile (16.6 KB)
    __shared__ int   sidx[CPB_][S_];          // ball-query results (2 KB)
    __shared__ float pp[CPB_][2];             // per-center partial sums
    __shared__ float red1[256], red2[256];    // batch reduce scratch

    const int blk  = blockIdx.x;
    const int tid  = threadIdx.x;
    const int w    = tid >> 6;                // wave 0..3
    const int lane = tid & 63;

    // ---------------- Phase A1: transpose two 64x64 feature tiles -------
    #pragma unroll
    for (int t = 0; t < 2; t++) {
        int ti = blk * 2 + t;                 // 0..1023 tiles
        int b  = ti >> 8;
        int n0 = (ti & 255) << 6;
        const float* fb = feat + (size_t)b * C_ * N_;
        #pragma unroll
        for (int cc = w; cc < 64; cc += 4)
            tile[cc][lane] = fb[(size_t)cc * N_ + n0 + lane];   // coalesced read
        __syncthreads();
        float* ftb = featT + (size_t)b * N_ * C_;
        #pragma unroll
        for (int nn = w; nn < 64; nn += 4)
            ftb[(size_t)(n0 + nn) * C_ + lane] = tile[lane][nn]; // coalesced write
        __syncthreads();                      // tile reuse guard
    }

    // ---------------- Phase A2: ball-query scan, 4 centers per wave -----
    for (int cc2 = 0; cc2 < 4; cc2++) {
        int ci = w * 4 + cc2;                 // 0..15
        int bm = blk * CPB_ + ci;
        int b  = bm >> 11;                    // M_ = 2048
        const float* pb = pts + (size_t)b * N_ * 3;
        float cx = ctr[(size_t)bm * 3 + 0];
        float cy = ctr[(size_t)bm * 3 + 1];
        float cz = ctr[(size_t)bm * 3 + 2];

        float xs[4], ys[4], zs[4], xn[4], yn[4], zn[4];
        #pragma unroll
        for (int r = 0; r < 4; r++) {
            int i = r * 64 + lane;
            xs[r] = pb[i * 3 + 0]; ys[r] = pb[i * 3 + 1]; zs[r] = pb[i * 3 + 2];
        }
        int cnt = 0;
        for (int base = 0; base < N_; base += 256) {
            int nxt = base + 256;
            if (nxt < N_) {
                #pragma unroll
                for (int r = 0; r < 4; r++) { // prefetch next trip (independent)
                    int i = nxt + r * 64 + lane;
                    xn[r] = pb[i * 3 + 0]; yn[r] = pb[i * 3 + 1]; zn[r] = pb[i * 3 + 2];
                }
            }
            #pragma unroll
            for (int r = 0; r < 4; r++) {
                // bit-exact vs numpy: no FMA contraction, (x^2 + y^2) + z^2 order
                float dx = __fsub_rn(cx, xs[r]);
                float dy = __fsub_rn(cy, ys[r]);
                float dz = __fsub_rn(cz, zs[r]);
                float d2 = __fadd_rn(__fadd_rn(__fmul_rn(dx, dx), __fmul_rn(dy, dy)),
                                     __fmul_rn(dz, dz));
                bool in = d2 < R2_;           // MIN_RADIUS=0: lower bound always true
                unsigned long long mk = __ballot(in);
                int rank = __popcll(mk & ((1ull << lane) - 1ull));
                int pos = cnt + rank;
                if (in && pos < S_) sidx[ci][pos] = base + r * 64 + lane;
                cnt += __popcll(mk);
                if (cnt >= S_) break;         // wave-uniform
            }
            if (cnt >= S_ || nxt >= N_) break;
            #pragma unroll
            for (int r = 0; r < 4; r++) { xs[r] = xn[r]; ys[r] = yn[r]; zs[r] = zn[r]; }
        }
        int cfound = cnt < S_ ? cnt : S_;
        if (lane < S_) {                      // pad: repeat first (0 if empty)
            int first = (cfound > 0) ? sidx[ci][0] : 0;
            int v = (lane < cfound) ? sidx[ci][lane] : first;
            sidx[ci][lane] = v;               // same-wave LDS, lockstep-safe
        }
    }

    gridsync(&syncc[0], NBLK_);               // all featT tiles written

    // ---------------- Phase B: centered partial sums, 4 centers/wave ----
    for (int cc2 = 0; cc2 < 4; cc2++) {
        int ci = w * 4 + cc2;
        int bm = blk * CPB_ + ci;
        int b  = bm >> 11;
        const float* pb  = pts + (size_t)b * N_ * 3;
        const float* ftb = featT + (size_t)b * N_ * C_;
        int id = sidx[ci][lane & 31];
        float cf = cfeat[(size_t)bm * C_ + lane];
        float cx = ctr[(size_t)bm * 3 + 0];
        float cy = ctr[(size_t)bm * 3 + 1];
        float cz = ctr[(size_t)bm * 3 + 2];

        float s1 = 0.f, s2 = 0.f;
        float v[S_];
        #pragma unroll
        for (int s = 0; s < S_; s++) {        // 32 independent coalesced row loads
            int p = __shfl(id, s);
            v[s] = ftb[(size_t)p * C_ + lane];
        }
        #pragma unroll
        for (int s = 0; s < S_; s++) { float d = v[s] - cf; s1 += d; s2 += d * d; }
        float cj = (lane < 32) ? cx : cy;     // xyz spread across half-waves
        float pv = pb[id * 3 + (lane >> 5)];
        float d0 = pv - cj; s1 += d0; s2 += d0 * d0;
        if (lane < 32) { float dz = pb[id * 3 + 2] - cz; s1 += dz; s2 += dz * dz; }
        #pragma unroll
        for (int off = 32; off > 0; off >>= 1) {
            s1 += __shfl_down(s1, off);
            s2 += __shfl_down(s2, off);
        }
        if (lane == 0) { pp[ci][0] = s1; pp[ci][1] = s2; }
    }
    __syncthreads();
    if (tid == 0) {                           // fixed-order block combine
        float a1 = 0.f, a2 = 0.f;
        #pragma unroll
        for (int i2 = 0; i2 < CPB_; i2++) { a1 += pp[i2][0]; a2 += pp[i2][1]; }
        bpart[blk * 2 + 0] = a1;
        bpart[blk * 2 + 1] = a2;
    }

    gridsync(&syncc[1], NBLK_);               // all block partials written

    // ---------------- Phase C: per-batch std (redundant, deterministic) -
    float inv;
    {
        int batch = blk >> 7;                 // 128 blocks per batch
        const float* bp = bpart + (size_t)batch * 128 * 2;
        red1[tid] = (tid < 128) ? bp[tid * 2 + 0] : 0.f;
        red2[tid] = (tid < 128) ? bp[tid * 2 + 1] : 0.f;
        __syncthreads();
        for (int off = 128; off > 0; off >>= 1) {
            if (tid < off) { red1[tid] += red1[tid + off]; red2[tid] += red2[tid + off]; }
            __syncthreads();
        }
        float sum = red1[0], sumsq = red2[0]; // identical in every block of batch
        const float n = (float)(M_ * S_ * J_);          // 4390912 < 2^24, exact
        float mean = sum / n;
        float var  = (sumsq - sum * mean) / (n - 1.f);  // ddof = 1
        inv = 1.f / (sqrtf(var) + EPS_);
    }

    // ---------------- Phase D: output (B, 67, M, S), 16 m's per block ---
    #pragma unroll
    for (int oc = 0; oc < 2; oc++) {
        int mi = oc * 8 + (tid >> 5);         // 0..15
        int s  = tid & 31;
        int bm = blk * CPB_ + mi;
        int b  = bm >> 11;
        int m  = bm & (M_ - 1);
        int p  = sidx[mi][s];
        const float* pb = pts + (size_t)b * N_ * 3;
        size_t obase = ((size_t)b * J_ * M_ + m) * S_ + s;
        #pragma unroll
        for (int j = 0; j < 3; j++) {
            float v2 = pb[p * 3 + j] - ctr[(size_t)bm * 3 + j];
            out[obase + (size_t)j * M_ * S_] = alpha[j] * inv * v2 + beta[j];
        }
        const float4* fr4 = (const float4*)(featT + ((size_t)b * N_ + p) * C_);
        const float4* cf4 = (const float4*)(cfeat + (size_t)bm * C_);
        #pragma unroll
        for (int cq = 0; cq < 16; cq++) {
            float4 fv = fr4[cq];
            float4 cv = cf4[cq];
            int j = 3 + cq * 4;
            out[obase + (size_t)(j + 0) * M_ * S_] = alpha[j + 0] * inv * (fv.x - cv.x) + beta[j + 0];
            out[obase + (size_t)(j + 1) * M_ * S_] = alpha[j + 1] * inv * (fv.y - cv.y) + beta[j + 1];
            out[obase + (size_t)(j + 2) * M_ * S_] = alpha[j + 2] * inv * (fv.z - cv.z) + beta[j + 2];
            out[obase + (size_t)(j + 3) * M_ * S_] = alpha[j + 3] * inv * (fv.w - cv.w) + beta[j + 3];
        }
    }
}

// ---------------------------------------------------------------------------
extern "C" void kernel_launch(void* const* d_in, const int* in_sizes, int n_in,
                              void* d_out, int out_size, void* d_ws, size_t ws_size,
                              hipStream_t stream) {
    const float* pts   = (const float*)d_in[0];   // (B,N,3)
    const float* ctr   = (const float*)d_in[1];   // (B,M,3)
    const float* cfeat = (const float*)d_in[2];   // (B,M,C)
    const float* feat  = (const float*)d_in[3];   // (B,C,N)
    const float* alpha = (const float*)d_in[4];   // (67)
    const float* beta  = (const float*)d_in[5];   // (67)
    float* out = (float*)d_out;

    // ws: featT 16 MB | bpart 4 KB | sync counters 8 B
    char* ws = (char*)d_ws;
    float* featT = (float*)ws;
    float* bpart = (float*)(ws + (size_t)B_ * N_ * C_ * 4);
    int*   syncc = (int*)(ws + (size_t)B_ * N_ * C_ * 4 + NBLK_ * 2 * 4);

    hipMemsetAsync(syncc, 0, 2 * sizeof(int), stream);   // reset barrier counters
    k_fused<<<NBLK_, 256, 0, stream>>>(pts, ctr, cfeat, feat, alpha, beta,
                                       featT, bpart, syncc, out);
}

// Round 5
// 65.413 us; speedup vs baseline: 3.4217x; 3.4217x over previous
//
#include <hip/hip_runtime.h>
#include <cstdint>
#include <cstddef>

#define B_ 4
#define N_ 16384
#define M_ 2048
#define C_ 64
#define S_ 32
#define J_ 67          // 3 + C
#define R2_ 0.04f
#define EPS_ 1e-5f

// ---------------------------------------------------------------------------
// KA: fused independent phases (restored round-3 structure, 3072 blocks).
//   blocks [0, 1024):    transpose features (B,C,N) -> featT (B,N,C)
//   blocks [1024, 3072): ball-query scan (idx only), 4 centers/block (1/wave)
// Scan: depth-2 software pipeline — 24 loads (512 points) in flight before
// processing; early-exit checked per 256-pt trip (stores gated by pos<S_).
// ---------------------------------------------------------------------------

// load trip of 256 points (4 rounds x 64 lanes) into register arrays
#define LD3(X, Y, Z, BASE)                                             \
    for (int r = 0; r < 4; r++) {                                      \
        int i = (BASE) + r * 64 + lane;                                \
        X[r] = pb[i * 3 + 0]; Y[r] = pb[i * 3 + 1]; Z[r] = pb[i * 3 + 2]; \
    }

// process one trip: bit-exact d2 (no FMA contraction, (x^2+y^2)+z^2 order)
#define PROC3(X, Y, Z, BASE)                                           \
    for (int r = 0; r < 4; r++) {                                      \
        float dx = __fsub_rn(cx, X[r]);                                \
        float dy = __fsub_rn(cy, Y[r]);                                \
        float dz = __fsub_rn(cz, Z[r]);                                \
        float d2 = __fadd_rn(__fadd_rn(__fmul_rn(dx, dx), __fmul_rn(dy, dy)), \
                             __fmul_rn(dz, dz));                       \
        bool in = d2 < R2_;                                            \
        unsigned long long mk = __ballot(in);                          \
        int rank = __popcll(mk & ((1ull << lane) - 1ull));             \
        int pos = cnt + rank;                                          \
        if (in && pos < S_) sidx[w * S_ + pos] = (BASE) + r * 64 + lane; \
        cnt += __popcll(mk);                                           \
    }

__global__ __launch_bounds__(256) void k_phase1(
        const float* __restrict__ feat, float* __restrict__ featT,
        const float* __restrict__ pts, const float* __restrict__ ctr,
        int* __restrict__ idx_ws) {
    __shared__ float tile[64][65];            // transpose tile; scan aliases sidx
    int blk = blockIdx.x;
    int tid = threadIdx.x;

    if (blk < 1024) {
        // ---- transpose role ----
        int b  = blk >> 8;                    // N_/64 = 256 tiles per batch
        int n0 = (blk & 255) << 6;
        int r = tid >> 6, i = tid & 63;
        const float* fb = feat + (size_t)b * C_ * N_;
        #pragma unroll
        for (int cc = r; cc < 64; cc += 4)
            tile[cc][i] = fb[(size_t)cc * N_ + n0 + i];     // coalesced read
        __syncthreads();
        float* ftb = featT + (size_t)b * N_ * C_;
        #pragma unroll
        for (int nn = r; nn < 64; nn += 4)
            ftb[(size_t)(n0 + nn) * C_ + i] = tile[i][nn];  // coalesced write
        return;
    }

    // ---- ball-query scan role (idx only), one center per wave ----
    int* sidx = (int*)&tile[0][0];            // [4][S_] per-wave slots
    int w    = tid >> 6;
    int lane = tid & 63;
    int bm   = (blk - 1024) * 4 + w;
    int b    = bm >> 11;                      // M_ = 2048
    const float* pb = pts + (size_t)b * N_ * 3;
    float cx = ctr[(size_t)bm * 3 + 0];
    float cy = ctr[(size_t)bm * 3 + 1];
    float cz = ctr[(size_t)bm * 3 + 2];

    float ax[4], ay[4], az[4], bx[4], by[4], bz[4];   // current 2 trips
    float px[4], py[4], pz[4], qx[4], qy[4], qz[4];   // prefetched 2 trips
    int cnt = 0;
    LD3(ax, ay, az, 0)
    LD3(bx, by, bz, 256)
    for (int base = 0; base < N_; base += 512) {
        int nb = base + 512;
        if (nb < N_) {                        // depth-2 prefetch: 24 loads in flight
            LD3(px, py, pz, nb)
            LD3(qx, qy, qz, nb + 256)
        }
        PROC3(ax, ay, az, base)
        if (cnt >= S_) break;                 // wave-uniform
        PROC3(bx, by, bz, base + 256)
        if (cnt >= S_ || nb >= N_) break;
        for (int r = 0; r < 4; r++) {
            ax[r] = px[r]; ay[r] = py[r]; az[r] = pz[r];
            bx[r] = qx[r]; by[r] = qy[r]; bz[r] = qz[r];
        }
    }
    __syncthreads();
    int cfound = cnt < S_ ? cnt : S_;
    if (lane < S_) {
        int first = (cfound > 0) ? sidx[w * S_] : 0;    // empty ball -> zeros
        int v = (lane < cfound) ? sidx[w * S_ + lane] : first;
        idx_ws[(size_t)bm * S_ + lane] = v;             // padded idx (ref semantics)
    }
}

// ---------------------------------------------------------------------------
// KB: per-center partial sums of centered values -> ONE partial per block
// (8 centers/block). Reassociated vs reference — only feeds the scalar std.
// ---------------------------------------------------------------------------
__global__ __launch_bounds__(256) void k_sums(
        const float* __restrict__ pts, const float* __restrict__ ctr,
        const float* __restrict__ featT, const float* __restrict__ cfeat,
        const int* __restrict__ idx_ws, float* __restrict__ bpart) {
    __shared__ float pp1[8], pp2[8];
    int w    = threadIdx.x >> 6;
    int lane = threadIdx.x & 63;
    #pragma unroll
    for (int cc = 0; cc < 2; cc++) {
        int ci = w * 2 + cc;
        int bm = blockIdx.x * 8 + ci;
        int b  = bm >> 11;
        const float* pb  = pts + (size_t)b * N_ * 3;
        const float* ftb = featT + (size_t)b * N_ * C_;
        int id = idx_ws[(size_t)bm * S_ + (lane & 31)];
        float cf = cfeat[(size_t)bm * C_ + lane];
        float cx = ctr[(size_t)bm * 3 + 0];
        float cy = ctr[(size_t)bm * 3 + 1];
        float cz = ctr[(size_t)bm * 3 + 2];

        float s1 = 0.f, s2 = 0.f;
        float v[S_];
        #pragma unroll
        for (int s = 0; s < S_; s++) {        // 32 independent coalesced row loads
            int p = __shfl(id, s);
            v[s] = ftb[(size_t)p * C_ + lane];
        }
        #pragma unroll
        for (int s = 0; s < S_; s++) { float d = v[s] - cf; s1 += d; s2 += d * d; }
        float cj = (lane < 32) ? cx : cy;     // xyz spread across half-waves
        float pv = pb[id * 3 + (lane >> 5)];
        float d0 = pv - cj; s1 += d0; s2 += d0 * d0;
        if (lane < 32) { float dz = pb[id * 3 + 2] - cz; s1 += dz; s2 += dz * dz; }
        #pragma unroll
        for (int off = 32; off > 0; off >>= 1) {
            s1 += __shfl_down(s1, off);
            s2 += __shfl_down(s2, off);
        }
        if (lane == 0) { pp1[ci] = s1; pp2[ci] = s2; }
    }
    __syncthreads();
    if (threadIdx.x == 0) {                   // fixed-order block combine
        float a1 = 0.f, a2 = 0.f;
        #pragma unroll
        for (int i = 0; i < 8; i++) { a1 += pp1[i]; a2 += pp2[i]; }
        bpart[blockIdx.x * 2 + 0] = a1;
        bpart[blockIdx.x * 2 + 1] = a2;
    }
}

// ---------------------------------------------------------------------------
// K3: inline per-batch std reduce (256 partials, fixed order — identical in
// every block of a batch) + output (B,67,M,S) with float4 stores.
// Thread = (m_local = tid>>3, sq = tid&7): 4 consecutive s per thread.
// ---------------------------------------------------------------------------
__global__ __launch_bounds__(256) void k_output(
        const float* __restrict__ pts, const float* __restrict__ ctr,
        const float* __restrict__ featT, const float* __restrict__ cfeat,
        const float* __restrict__ alpha, const float* __restrict__ beta,
        const int* __restrict__ idx_ws, const float* __restrict__ bpart,
        float* __restrict__ out) {
    __shared__ float r1[256], r2[256];
    int blk = blockIdx.x, tid = threadIdx.x;
    int batch = blk >> 6;                     // 64 blocks per batch

    // --- per-batch std (deterministic tree over 256 block-partials) ---
    const float* bp = bpart + (size_t)batch * 256 * 2;
    r1[tid] = bp[tid * 2 + 0];
    r2[tid] = bp[tid * 2 + 1];
    __syncthreads();
    for (int off = 128; off > 0; off >>= 1) {
        if (tid < off) { r1[tid] += r1[tid + off]; r2[tid] += r2[tid + off]; }
        __syncthreads();
    }
    float sum = r1[0], sumsq = r2[0];
    const float n = (float)(M_ * S_ * J_);            // 4390912 < 2^24, exact
    float mean = sum / n;
    float var  = (sumsq - sum * mean) / (n - 1.f);    // ddof = 1
    float inv  = 1.f / (sqrtf(var) + EPS_);

    // --- output ---
    int m  = (blk & 63) * 32 + (tid >> 3);    // 32 m's per block
    int sq = tid & 7;
    int s0 = sq * 4;
    size_t bm = (size_t)batch * M_ + m;
    int4 pidx = *(const int4*)(idx_ws + bm * S_ + s0);
    const float* pb = pts + (size_t)batch * N_ * 3;
    size_t obase = ((size_t)batch * J_ * M_ + m) * (size_t)S_ + s0;

    #pragma unroll
    for (int j = 0; j < 3; j++) {             // xyz rows
        float a = alpha[j] * inv, bt = beta[j];
        float cj = ctr[bm * 3 + j];
        float4 o;
        o.x = a * (pb[pidx.x * 3 + j] - cj) + bt;
        o.y = a * (pb[pidx.y * 3 + j] - cj) + bt;
        o.z = a * (pb[pidx.z * 3 + j] - cj) + bt;
        o.w = a * (pb[pidx.w * 3 + j] - cj) + bt;
        *(float4*)(out + obase + (size_t)j * (M_ * S_)) = o;
    }
    const float4* f0 = (const float4*)(featT + ((size_t)batch * N_ + pidx.x) * C_);
    const float4* f1 = (const float4*)(featT + ((size_t)batch * N_ + pidx.y) * C_);
    const float4* f2 = (const float4*)(featT + ((size_t)batch * N_ + pidx.z) * C_);
    const float4* f3 = (const float4*)(featT + ((size_t)batch * N_ + pidx.w) * C_);
    const float4* cf = (const float4*)(cfeat + bm * C_);
    #pragma unroll 2
    for (int cq = 0; cq < 16; cq++) {
        float4 v0 = f0[cq], v1 = f1[cq], v2 = f2[cq], v3 = f3[cq], c = cf[cq];
        int j = 3 + cq * 4;
        float a0 = alpha[j + 0] * inv, b0 = beta[j + 0];
        float a1 = alpha[j + 1] * inv, b1 = beta[j + 1];
        float a2 = alpha[j + 2] * inv, b2 = beta[j + 2];
        float a3 = alpha[j + 3] * inv, b3 = beta[j + 3];
        float4 o0, o1, o2, o3;                // transpose 4x4 block in regs
        o0.x = a0 * (v0.x - c.x) + b0; o0.y = a0 * (v1.x - c.x) + b0;
        o0.z = a0 * (v2.x - c.x) + b0; o0.w = a0 * (v3.x - c.x) + b0;
        o1.x = a1 * (v0.y - c.y) + b1; o1.y = a1 * (v1.y - c.y) + b1;
        o1.z = a1 * (v2.y - c.y) + b1; o1.w = a1 * (v3.y - c.y) + b1;
        o2.x = a2 * (v0.z - c.z) + b2; o2.y = a2 * (v1.z - c.z) + b2;
        o2.z = a2 * (v2.z - c.z) + b2; o2.w = a2 * (v3.z - c.z) + b2;
        o3.x = a3 * (v0.w - c.w) + b3; o3.y = a3 * (v1.w - c.w) + b3;
        o3.z = a3 * (v2.w - c.w) + b3; o3.w = a3 * (v3.w - c.w) + b3;
        *(float4*)(out + obase + (size_t)(j + 0) * (M_ * S_)) = o0;
        *(float4*)(out + obase + (size_t)(j + 1) * (M_ * S_)) = o1;
        *(float4*)(out + obase + (size_t)(j + 2) * (M_ * S_)) = o2;
        *(float4*)(out + obase + (size_t)(j + 3) * (M_ * S_)) = o3;
    }
}

// ---------------------------------------------------------------------------
extern "C" void kernel_launch(void* const* d_in, const int* in_sizes, int n_in,
                              void* d_out, int out_size, void* d_ws, size_t ws_size,
                              hipStream_t stream) {
    const float* pts   = (const float*)d_in[0];   // (B,N,3)
    const float* ctr   = (const float*)d_in[1];   // (B,M,3)
    const float* cfeat = (const float*)d_in[2];   // (B,M,C)
    const float* feat  = (const float*)d_in[3];   // (B,C,N)
    const float* alpha = (const float*)d_in[4];   // (67)
    const float* beta  = (const float*)d_in[5];   // (67)
    float* out = (float*)d_out;

    // ws: featT 16 MB | idx 1 MB | bpart 8 KB
    char* ws = (char*)d_ws;
    float* featT = (float*)ws;
    int*   idx_ws = (int*)(ws + (size_t)B_ * N_ * C_ * 4);
    float* bpart = (float*)(ws + (size_t)B_ * N_ * C_ * 4 + (size_t)B_ * M_ * S_ * 4);

    k_phase1<<<3072, 256, 0, stream>>>(feat, featT, pts, ctr, idx_ws);
    k_sums<<<B_ * M_ / 8, 256, 0, stream>>>(pts, ctr, featT, cfeat, idx_ws, bpart);
    k_output<<<256, 256, 0, stream>>>(pts, ctr, featT, cfeat, alpha, beta,
                                      idx_ws, bpart, out);
}

// Round 6
// 48.935 us; speedup vs baseline: 4.5739x; 1.3367x over previous
//
#include <hip/hip_runtime.h>
#include <cstdint>
#include <cstddef>

#define B_ 4
#define N_ 16384
#define M_ 2048
#define C_ 64
#define S_ 32
#define J_ 67          // 3 + C
#define R2_ 0.04f
#define EPS_ 1e-5f

// ---------------------------------------------------------------------------
// KA: fused independent phases (round-3 structure, 3072 blocks).
//   blocks [0, 1024):    transpose features (B,C,N) -> featT (B,N,C)
//   blocks [1024, 3072): ball-query scan (idx only), 4 centers/block (1/wave)
// Scan: depth-1 software pipeline + per-round wave-uniform early exit
// (measured best in round 3).
// ---------------------------------------------------------------------------
__global__ __launch_bounds__(256) void k_phase1(
        const float* __restrict__ feat, float* __restrict__ featT,
        const float* __restrict__ pts, const float* __restrict__ ctr,
        int* __restrict__ idx_ws) {
    __shared__ float tile[64][65];            // transpose tile; scan aliases sidx
    int blk = blockIdx.x;
    int tid = threadIdx.x;

    if (blk < 1024) {
        // ---- transpose role ----
        int b  = blk >> 8;                    // N_/64 = 256 tiles per batch
        int n0 = (blk & 255) << 6;
        int r = tid >> 6, i = tid & 63;
        const float* fb = feat + (size_t)b * C_ * N_;
        #pragma unroll
        for (int cc = r; cc < 64; cc += 4)
            tile[cc][i] = fb[(size_t)cc * N_ + n0 + i];     // coalesced read
        __syncthreads();
        float* ftb = featT + (size_t)b * N_ * C_;
        #pragma unroll
        for (int nn = r; nn < 64; nn += 4)
            ftb[(size_t)(n0 + nn) * C_ + i] = tile[i][nn];  // coalesced write
        return;
    }

    // ---- ball-query scan role (idx only), one center per wave ----
    int* sidx = (int*)&tile[0][0];            // [4][S_] per-wave slots
    int w    = tid >> 6;
    int lane = tid & 63;
    int bm   = (blk - 1024) * 4 + w;
    int b    = bm >> 11;                      // M_ = 2048
    const float* pb = pts + (size_t)b * N_ * 3;
    float cx = ctr[(size_t)bm * 3 + 0];
    float cy = ctr[(size_t)bm * 3 + 1];
    float cz = ctr[(size_t)bm * 3 + 2];

    // software-pipelined scan: issue trip t+1 loads before processing trip t
    float xs[4], ys[4], zs[4], xn[4], yn[4], zn[4];
    #pragma unroll
    for (int r = 0; r < 4; r++) {
        int i = r * 64 + lane;
        xs[r] = pb[i * 3 + 0]; ys[r] = pb[i * 3 + 1]; zs[r] = pb[i * 3 + 2];
    }
    int cnt = 0;
    for (int base = 0; base < N_; base += 256) {
        int nxt = base + 256;
        if (nxt < N_) {
            #pragma unroll
            for (int r = 0; r < 4; r++) {     // prefetch next trip (independent)
                int i = nxt + r * 64 + lane;
                xn[r] = pb[i * 3 + 0]; yn[r] = pb[i * 3 + 1]; zn[r] = pb[i * 3 + 2];
            }
        }
        #pragma unroll
        for (int r = 0; r < 4; r++) {
            // bit-exact vs numpy: no FMA contraction, (x^2 + y^2) + z^2 order
            float dx = __fsub_rn(cx, xs[r]);
            float dy = __fsub_rn(cy, ys[r]);
            float dz = __fsub_rn(cz, zs[r]);
            float d2 = __fadd_rn(__fadd_rn(__fmul_rn(dx, dx), __fmul_rn(dy, dy)),
                                 __fmul_rn(dz, dz));
            bool in = d2 < R2_;               // MIN_RADIUS=0: lower bound always true
            unsigned long long mk = __ballot(in);
            int rank = __popcll(mk & ((1ull << lane) - 1ull));
            int pos = cnt + rank;
            if (in && pos < S_) sidx[w * S_ + pos] = base + r * 64 + lane;
            cnt += __popcll(mk);
            if (cnt >= S_) break;             // wave-uniform
        }
        if (cnt >= S_ || nxt >= N_) break;
        #pragma unroll
        for (int r = 0; r < 4; r++) { xs[r] = xn[r]; ys[r] = yn[r]; zs[r] = zn[r]; }
    }
    __syncthreads();                          // order LDS scatter vs cross-lane read
    int cfound = cnt < S_ ? cnt : S_;
    if (lane < S_) {
        int first = (cfound > 0) ? sidx[w * S_] : 0;    // empty ball -> zeros
        int v = (lane < cfound) ? sidx[w * S_ + lane] : first;
        idx_ws[(size_t)bm * S_ + lane] = v;             // padded idx (ref semantics)
    }
}

// ---------------------------------------------------------------------------
// KB: per-center partial sums of centered values -> ONE partial per block
// (8 centers/block, 1024 blocks). Reassociated — only feeds the scalar std.
// ---------------------------------------------------------------------------
__global__ __launch_bounds__(256) void k_sums(
        const float* __restrict__ pts, const float* __restrict__ ctr,
        const float* __restrict__ featT, const float* __restrict__ cfeat,
        const int* __restrict__ idx_ws, float* __restrict__ bpart) {
    __shared__ float pp1[8], pp2[8];
    int w    = threadIdx.x >> 6;
    int lane = threadIdx.x & 63;
    #pragma unroll
    for (int cc = 0; cc < 2; cc++) {
        int ci = w * 2 + cc;
        int bm = blockIdx.x * 8 + ci;
        int b  = bm >> 11;
        const float* pb  = pts + (size_t)b * N_ * 3;
        const float* ftb = featT + (size_t)b * N_ * C_;
        int id = idx_ws[(size_t)bm * S_ + (lane & 31)];
        float cf = cfeat[(size_t)bm * C_ + lane];
        float cx = ctr[(size_t)bm * 3 + 0];
        float cy = ctr[(size_t)bm * 3 + 1];
        float cz = ctr[(size_t)bm * 3 + 2];

        float s1 = 0.f, s2 = 0.f;
        float v[S_];
        #pragma unroll
        for (int s = 0; s < S_; s++) {        // 32 independent coalesced row loads
            int p = __shfl(id, s);
            v[s] = ftb[(size_t)p * C_ + lane];
        }
        #pragma unroll
        for (int s = 0; s < S_; s++) { float d = v[s] - cf; s1 += d; s2 += d * d; }
        float cj = (lane < 32) ? cx : cy;     // xyz spread across half-waves
        float pv = pb[id * 3 + (lane >> 5)];
        float d0 = pv - cj; s1 += d0; s2 += d0 * d0;
        if (lane < 32) { float dz = pb[id * 3 + 2] - cz; s1 += dz; s2 += dz * dz; }
        #pragma unroll
        for (int off = 32; off > 0; off >>= 1) {
            s1 += __shfl_down(s1, off);
            s2 += __shfl_down(s2, off);
        }
        if (lane == 0) { pp1[ci] = s1; pp2[ci] = s2; }
    }
    __syncthreads();
    if (threadIdx.x == 0) {                   // fixed-order block combine
        float a1 = 0.f, a2 = 0.f;
        #pragma unroll
        for (int i = 0; i < 8; i++) { a1 += pp1[i]; a2 += pp2[i]; }
        bpart[blockIdx.x * 2 + 0] = a1;
        bpart[blockIdx.x * 2 + 1] = a2;
    }
}

// ---------------------------------------------------------------------------
// K3: inline per-batch std reduce (256 partials, fixed order — identical in
// every block of a batch) + output (B,67,M,S) with float4 stores.
// 1024 blocks (4/CU): thread = (mi = tid>>5, cg = (tid>>3)&3, sq = tid&7).
// Each thread: 4-row gather (64 B per row) + 16 float4 stores; cg 0 adds xyz.
// ---------------------------------------------------------------------------
__global__ __launch_bounds__(256) void k_output(
        const float* __restrict__ pts, const float* __restrict__ ctr,
        const float* __restrict__ featT, const float* __restrict__ cfeat,
        const float* __restrict__ alpha, const float* __restrict__ beta,
        const int* __restrict__ idx_ws, const float* __restrict__ bpart,
        float* __restrict__ out) {
    __shared__ float r1[256], r2[256];
    int blk = blockIdx.x, tid = threadIdx.x;
    int batch = blk >> 8;                     // 256 blocks per batch

    // --- per-batch std (deterministic tree over 256 block-partials) ---
    const float* bp = bpart + (size_t)batch * 256 * 2;
    r1[tid] = bp[tid * 2 + 0];
    r2[tid] = bp[tid * 2 + 1];
    __syncthreads();
    for (int off = 128; off > 0; off >>= 1) {
        if (tid < off) { r1[tid] += r1[tid + off]; r2[tid] += r2[tid + off]; }
        __syncthreads();
    }
    float sum = r1[0], sumsq = r2[0];
    const float n = (float)(M_ * S_ * J_);            // 4390912 < 2^24, exact
    float mean = sum / n;
    float var  = (sumsq - sum * mean) / (n - 1.f);    // ddof = 1
    float inv  = 1.f / (sqrtf(var) + EPS_);

    // --- output: 8 m's per block, channels split across 4 thread-groups ---
    int mi = tid >> 5;                        // 0..7
    int cg = (tid >> 3) & 3;                  // channel group: 16 channels each
    int sq = tid & 7;                         // s-quad
    int m  = (blk & 255) * 8 + mi;
    int s0 = sq * 4;
    size_t bm = (size_t)batch * M_ + m;
    int4 pidx = *(const int4*)(idx_ws + bm * S_ + s0);
    const float* pb = pts + (size_t)batch * N_ * 3;
    size_t obase = ((size_t)batch * J_ * M_ + m) * (size_t)S_ + s0;

    if (cg == 0) {                            // xyz rows
        #pragma unroll
        for (int j = 0; j < 3; j++) {
            float a = alpha[j] * inv, bt = beta[j];
            float cj = ctr[bm * 3 + j];
            float4 o;
            o.x = a * (pb[pidx.x * 3 + j] - cj) + bt;
            o.y = a * (pb[pidx.y * 3 + j] - cj) + bt;
            o.z = a * (pb[pidx.z * 3 + j] - cj) + bt;
            o.w = a * (pb[pidx.w * 3 + j] - cj) + bt;
            *(float4*)(out + obase + (size_t)j * (M_ * S_)) = o;
        }
    }
    const float4* f0 = (const float4*)(featT + ((size_t)batch * N_ + pidx.x) * C_);
    const float4* f1 = (const float4*)(featT + ((size_t)batch * N_ + pidx.y) * C_);
    const float4* f2 = (const float4*)(featT + ((size_t)batch * N_ + pidx.z) * C_);
    const float4* f3 = (const float4*)(featT + ((size_t)batch * N_ + pidx.w) * C_);
    const float4* cf = (const float4*)(cfeat + bm * C_);
    #pragma unroll
    for (int cq = cg * 4; cq < cg * 4 + 4; cq++) {
        float4 v0 = f0[cq], v1 = f1[cq], v2 = f2[cq], v3 = f3[cq], c = cf[cq];
        int j = 3 + cq * 4;
        float a0 = alpha[j + 0] * inv, b0 = beta[j + 0];
        float a1 = alpha[j + 1] * inv, b1 = beta[j + 1];
        float a2 = alpha[j + 2] * inv, b2 = beta[j + 2];
        float a3 = alpha[j + 3] * inv, b3 = beta[j + 3];
        float4 o0, o1, o2, o3;                // transpose 4x4 block in regs
        o0.x = a0 * (v0.x - c.x) + b0; o0.y = a0 * (v1.x - c.x) + b0;
        o0.z = a0 * (v2.x - c.x) + b0; o0.w = a0 * (v3.x - c.x) + b0;
        o1.x = a1 * (v0.y - c.y) + b1; o1.y = a1 * (v1.y - c.y) + b1;
        o1.z = a1 * (v2.y - c.y) + b1; o1.w = a1 * (v3.y - c.y) + b1;
        o2.x = a2 * (v0.z - c.z) + b2; o2.y = a2 * (v1.z - c.z) + b2;
        o2.z = a2 * (v2.z - c.z) + b2; o2.w = a2 * (v3.z - c.z) + b2;
        o3.x = a3 * (v0.w - c.w) + b3; o3.y = a3 * (v1.w - c.w) + b3;
        o3.z = a3 * (v2.w - c.w) + b3; o3.w = a3 * (v3.w - c.w) + b3;
        *(float4*)(out + obase + (size_t)(j + 0) * (M_ * S_)) = o0;
        *(float4*)(out + obase + (size_t)(j + 1) * (M_ * S_)) = o1;
        *(float4*)(out + obase + (size_t)(j + 2) * (M_ * S_)) = o2;
        *(float4*)(out + obase + (size_t)(j + 3) * (M_ * S_)) = o3;
    }
}

// ---------------------------------------------------------------------------
extern "C" void kernel_launch(void* const* d_in, const int* in_sizes, int n_in,
                              void* d_out, int out_size, void* d_ws, size_t ws_size,
                              hipStream_t stream) {
    const float* pts   = (const float*)d_in[0];   // (B,N,3)
    const float* ctr   = (const float*)d_in[1];   // (B,M,3)
    const float* cfeat = (const float*)d_in[2];   // (B,M,C)
    const float* feat  = (const float*)d_in[3];   // (B,C,N)
    const float* alpha = (const float*)d_in[4];   // (67)
    const float* beta  = (const float*)d_in[5];   // (67)
    float* out = (float*)d_out;

    // ws: featT 16 MB | idx 1 MB | bpart 8 KB
    char* ws = (char*)d_ws;
    float* featT = (float*)ws;
    int*   idx_ws = (int*)(ws + (size_t)B_ * N_ * C_ * 4);
    float* bpart = (float*)(ws + (size_t)B_ * N_ * C_ * 4 + (size_t)B_ * M_ * S_ * 4);

    k_phase1<<<3072, 256, 0, stream>>>(feat, featT, pts, ctr, idx_ws);
    k_sums<<<B_ * M_ / 8, 256, 0, stream>>>(pts, ctr, featT, cfeat, idx_ws, bpart);
    k_output<<<1024, 256, 0, stream>>>(pts, ctr, featT, cfeat, alpha, beta,
                                       idx_ws, bpart, out);
}

// Round 7
// 48.754 us; speedup vs baseline: 4.5909x; 1.0037x over previous
//
#include <hip/hip_runtime.h>
#include <cstdint>
#include <cstddef>

#define B_ 4
#define N_ 16384
#define M_ 2048
#define C_ 64
#define S_ 32
#define J_ 67          // 3 + C
#define R2_ 0.04f
#define EPS_ 1e-5f

// ---------------------------------------------------------------------------
// KA: fused independent phases.
//   blocks [0, 1024):    transpose features (B,C,N) -> featT (B,N,C)
//   blocks [1024, 9216): ball-query scan, ONE CENTER PER BLOCK (4 waves).
// Scan round = 1024 points: wave w covers chunk base+w*256 (R3-style 4-round
// ballot selection, bit-exact), then LDS combine concatenates wave segments
// in chunk order == ascending index order. Early exit when total >= 32.
// 4x shorter serial critical path than 1-wave-per-center.
// ---------------------------------------------------------------------------
__global__ __launch_bounds__(256) void k_phase1(
        const float* __restrict__ feat, float* __restrict__ featT,
        const float* __restrict__ pts, const float* __restrict__ ctr,
        int* __restrict__ idx_ws) {
    __shared__ float tile[64][65];            // transpose tile (16.6 KB)
    int blk = blockIdx.x;
    int tid = threadIdx.x;

    if (blk < 1024) {
        // ---- transpose role ----
        int b  = blk >> 8;                    // N_/64 = 256 tiles per batch
        int n0 = (blk & 255) << 6;
        int r = tid >> 6, i = tid & 63;
        const float* fb = feat + (size_t)b * C_ * N_;
        #pragma unroll
        for (int cc = r; cc < 64; cc += 4)
            tile[cc][i] = fb[(size_t)cc * N_ + n0 + i];     // coalesced read
        __syncthreads();
        float* ftb = featT + (size_t)b * N_ * C_;
        #pragma unroll
        for (int nn = r; nn < 64; nn += 4)
            ftb[(size_t)(n0 + nn) * C_ + i] = tile[i][nn];  // coalesced write
        return;
    }

    // ---- ball-query scan role: one center per block, 4 waves ----
    __shared__ int wcnt[4];                   // per-wave in-chunk count (round)
    __shared__ int widx[4][S_];               // per-wave first-32 chunk indices
    __shared__ int result[S_];                // combined first-32 (ascending)
    int w    = tid >> 6;
    int lane = tid & 63;
    int bm   = blk - 1024;                    // 0..8191
    int b    = bm >> 11;                      // M_ = 2048
    const float* pb = pts + (size_t)b * N_ * 3;
    float cx = ctr[(size_t)bm * 3 + 0];
    float cy = ctr[(size_t)bm * 3 + 1];
    float cz = ctr[(size_t)bm * 3 + 2];

    float xs[4], ys[4], zs[4], xn[4], yn[4], zn[4];
    #pragma unroll
    for (int r = 0; r < 4; r++) {             // round 0 chunk loads
        int i = w * 256 + r * 64 + lane;
        xs[r] = pb[i * 3 + 0]; ys[r] = pb[i * 3 + 1]; zs[r] = pb[i * 3 + 2];
    }
    int total = 0;
    for (int base = 0; base < N_; base += 1024) {
        int nb = base + 1024;
        if (nb < N_) {
            #pragma unroll
            for (int r = 0; r < 4; r++) {     // prefetch next round's chunk
                int i = nb + w * 256 + r * 64 + lane;
                xn[r] = pb[i * 3 + 0]; yn[r] = pb[i * 3 + 1]; zn[r] = pb[i * 3 + 2];
            }
        }
        int cbase = base + w * 256;
        int cnt = 0;                          // within-chunk count
        #pragma unroll
        for (int r = 0; r < 4; r++) {
            // bit-exact vs numpy: no FMA contraction, (x^2 + y^2) + z^2 order
            float dx = __fsub_rn(cx, xs[r]);
            float dy = __fsub_rn(cy, ys[r]);
            float dz = __fsub_rn(cz, zs[r]);
            float d2 = __fadd_rn(__fadd_rn(__fmul_rn(dx, dx), __fmul_rn(dy, dy)),
                                 __fmul_rn(dz, dz));
            bool in = d2 < R2_;               // MIN_RADIUS=0: lower bound always true
            unsigned long long mk = __ballot(in);
            int rank = __popcll(mk & ((1ull << lane) - 1ull));
            int pos = cnt + rank;
            if (in && pos < S_) widx[w][pos] = cbase + r * 64 + lane;
            cnt += __popcll(mk);
        }
        if (lane == 0) wcnt[w] = cnt;
        __syncthreads();                      // wcnt/widx visible to all
        int c0 = wcnt[0], c1 = wcnt[1], c2 = wcnt[2], c3 = wcnt[3];
        int offw = total + ((w > 0) ? c0 : 0) + ((w > 1) ? c1 : 0) + ((w > 2) ? c2 : 0);
        int cw = wcnt[w] < S_ ? wcnt[w] : S_;
        if (lane < cw) {                      // concat wave segments, chunk order
            int dst = offw + lane;
            if (dst < S_) result[dst] = widx[w][lane];
        }
        __syncthreads();                      // result stable; widx reusable
        total += c0 + c1 + c2 + c3;
        if (total >= S_ || nb >= N_) break;   // block-uniform
        #pragma unroll
        for (int r = 0; r < 4; r++) { xs[r] = xn[r]; ys[r] = yn[r]; zs[r] = zn[r]; }
    }
    int cfound = total < S_ ? total : S_;
    if (tid < S_) {
        int first = (cfound > 0) ? result[0] : 0;       // empty ball -> zeros
        int v = (tid < cfound) ? result[tid] : first;
        idx_ws[(size_t)bm * S_ + tid] = v;              // padded idx (ref semantics)
    }
}

// ---------------------------------------------------------------------------
// KB: per-center partial sums of centered values -> ONE partial per block
// (8 centers/block, 1024 blocks). Reassociated — only feeds the scalar std.
// ---------------------------------------------------------------------------
__global__ __launch_bounds__(256) void k_sums(
        const float* __restrict__ pts, const float* __restrict__ ctr,
        const float* __restrict__ featT, const float* __restrict__ cfeat,
        const int* __restrict__ idx_ws, float* __restrict__ bpart) {
    __shared__ float pp1[8], pp2[8];
    int w    = threadIdx.x >> 6;
    int lane = threadIdx.x & 63;
    #pragma unroll
    for (int cc = 0; cc < 2; cc++) {
        int ci = w * 2 + cc;
        int bm = blockIdx.x * 8 + ci;
        int b  = bm >> 11;
        const float* pb  = pts + (size_t)b * N_ * 3;
        const float* ftb = featT + (size_t)b * N_ * C_;
        int id = idx_ws[(size_t)bm * S_ + (lane & 31)];
        float cf = cfeat[(size_t)bm * C_ + lane];
        float cx = ctr[(size_t)bm * 3 + 0];
        float cy = ctr[(size_t)bm * 3 + 1];
        float cz = ctr[(size_t)bm * 3 + 2];

        float s1 = 0.f, s2 = 0.f;
        float v[S_];
        #pragma unroll
        for (int s = 0; s < S_; s++) {        // 32 independent coalesced row loads
            int p = __shfl(id, s);
            v[s] = ftb[(size_t)p * C_ + lane];
        }
        #pragma unroll
        for (int s = 0; s < S_; s++) { float d = v[s] - cf; s1 += d; s2 += d * d; }
        float cj = (lane < 32) ? cx : cy;     // xyz spread across half-waves
        float pv = pb[id * 3 + (lane >> 5)];
        float d0 = pv - cj; s1 += d0; s2 += d0 * d0;
        if (lane < 32) { float dz = pb[id * 3 + 2] - cz; s1 += dz; s2 += dz * dz; }
        #pragma unroll
        for (int off = 32; off > 0; off >>= 1) {
            s1 += __shfl_down(s1, off);
            s2 += __shfl_down(s2, off);
        }
        if (lane == 0) { pp1[ci] = s1; pp2[ci] = s2; }
    }
    __syncthreads();
    if (threadIdx.x == 0) {                   // fixed-order block combine
        float a1 = 0.f, a2 = 0.f;
        #pragma unroll
        for (int i = 0; i < 8; i++) { a1 += pp1[i]; a2 += pp2[i]; }
        bpart[blockIdx.x * 2 + 0] = a1;
        bpart[blockIdx.x * 2 + 1] = a2;
    }
}

// ---------------------------------------------------------------------------
// K3: inline per-batch std reduce (256 partials, fixed order — identical in
// every block of a batch) + output (B,67,M,S) with float4 stores.
// 1024 blocks (4/CU): thread = (mi = tid>>5, cg = (tid>>3)&3, sq = tid&7).
// Each thread: 4-row gather (64 B per row) + 16 float4 stores; cg 0 adds xyz.
// ---------------------------------------------------------------------------
__global__ __launch_bounds__(256) void k_output(
        const float* __restrict__ pts, const float* __restrict__ ctr,
        const float* __restrict__ featT, const float* __restrict__ cfeat,
        const float* __restrict__ alpha, const float* __restrict__ beta,
        const int* __restrict__ idx_ws, const float* __restrict__ bpart,
        float* __restrict__ out) {
    __shared__ float r1[256], r2[256];
    int blk = blockIdx.x, tid = threadIdx.x;
    int batch = blk >> 8;                     // 256 blocks per batch

    // --- per-batch std (deterministic tree over 256 block-partials) ---
    const float* bp = bpart + (size_t)batch * 256 * 2;
    r1[tid] = bp[tid * 2 + 0];
    r2[tid] = bp[tid * 2 + 1];
    __syncthreads();
    for (int off = 128; off > 0; off >>= 1) {
        if (tid < off) { r1[tid] += r1[tid + off]; r2[tid] += r2[tid + off]; }
        __syncthreads();
    }
    float sum = r1[0], sumsq = r2[0];
    const float n = (float)(M_ * S_ * J_);            // 4390912 < 2^24, exact
    float mean = sum / n;
    float var  = (sumsq - sum * mean) / (n - 1.f);    // ddof = 1
    float inv  = 1.f / (sqrtf(var) + EPS_);

    // --- output: 8 m's per block, channels split across 4 thread-groups ---
    int mi = tid >> 5;                        // 0..7
    int cg = (tid >> 3) & 3;                  // channel group: 16 channels each
    int sq = tid & 7;                         // s-quad
    int m  = (blk & 255) * 8 + mi;
    int s0 = sq * 4;
    size_t bm = (size_t)batch * M_ + m;
    int4 pidx = *(const int4*)(idx_ws + bm * S_ + s0);
    const float* pb = pts + (size_t)batch * N_ * 3;
    size_t obase = ((size_t)batch * J_ * M_ + m) * (size_t)S_ + s0;

    if (cg == 0) {                            // xyz rows
        #pragma unroll
        for (int j = 0; j < 3; j++) {
            float a = alpha[j] * inv, bt = beta[j];
            float cj = ctr[bm * 3 + j];
            float4 o;
            o.x = a * (pb[pidx.x * 3 + j] - cj) + bt;
            o.y = a * (pb[pidx.y * 3 + j] - cj) + bt;
            o.z = a * (pb[pidx.z * 3 + j] - cj) + bt;
            o.w = a * (pb[pidx.w * 3 + j] - cj) + bt;
            *(float4*)(out + obase + (size_t)j * (M_ * S_)) = o;
        }
    }
    const float4* f0 = (const float4*)(featT + ((size_t)batch * N_ + pidx.x) * C_);
    const float4* f1 = (const float4*)(featT + ((size_t)batch * N_ + pidx.y) * C_);
    const float4* f2 = (const float4*)(featT + ((size_t)batch * N_ + pidx.z) * C_);
    const float4* f3 = (const float4*)(featT + ((size_t)batch * N_ + pidx.w) * C_);
    const float4* cf = (const float4*)(cfeat + bm * C_);
    #pragma unroll
    for (int cq = cg * 4; cq < cg * 4 + 4; cq++) {
        float4 v0 = f0[cq], v1 = f1[cq], v2 = f2[cq], v3 = f3[cq], c = cf[cq];
        int j = 3 + cq * 4;
        float a0 = alpha[j + 0] * inv, b0 = beta[j + 0];
        float a1 = alpha[j + 1] * inv, b1 = beta[j + 1];
        float a2 = alpha[j + 2] * inv, b2 = beta[j + 2];
        float a3 = alpha[j + 3] * inv, b3 = beta[j + 3];
        float4 o0, o1, o2, o3;                // transpose 4x4 block in regs
        o0.x = a0 * (v0.x - c.x) + b0; o0.y = a0 * (v1.x - c.x) + b0;
        o0.z = a0 * (v2.x - c.x) + b0; o0.w = a0 * (v3.x - c.x) + b0;
        o1.x = a1 * (v0.y - c.y) + b1; o1.y = a1 * (v1.y - c.y) + b1;
        o1.z = a1 * (v2.y - c.y) + b1; o1.w = a1 * (v3.y - c.y) + b1;
        o2.x = a2 * (v0.z - c.z) + b2; o2.y = a2 * (v1.z - c.z) + b2;
        o2.z = a2 * (v2.z - c.z) + b2; o2.w = a2 * (v3.z - c.z) + b2;
        o3.x = a3 * (v0.w - c.w) + b3; o3.y = a3 * (v1.w - c.w) + b3;
        o3.z = a3 * (v2.w - c.w) + b3; o3.w = a3 * (v3.w - c.w) + b3;
        *(float4*)(out + obase + (size_t)(j + 0) * (M_ * S_)) = o0;
        *(float4*)(out + obase + (size_t)(j + 1) * (M_ * S_)) = o1;
        *(float4*)(out + obase + (size_t)(j + 2) * (M_ * S_)) = o2;
        *(float4*)(out + obase + (size_t)(j + 3) * (M_ * S_)) = o3;
    }
}

// ---------------------------------------------------------------------------
extern "C" void kernel_launch(void* const* d_in, const int* in_sizes, int n_in,
                              void* d_out, int out_size, void* d_ws, size_t ws_size,
                              hipStream_t stream) {
    const float* pts   = (const float*)d_in[0];   // (B,N,3)
    const float* ctr   = (const float*)d_in[1];   // (B,M,3)
    const float* cfeat = (const float*)d_in[2];   // (B,M,C)
    const float* feat  = (const float*)d_in[3];   // (B,C,N)
    const float* alpha = (const float*)d_in[4];   // (67)
    const float* beta  = (const float*)d_in[5];   // (67)
    float* out = (float*)d_out;

    // ws: featT 16 MB | idx 1 MB | bpart 8 KB
    char* ws = (char*)d_ws;
    float* featT = (float*)ws;
    int*   idx_ws = (int*)(ws + (size_t)B_ * N_ * C_ * 4);
    float* bpart = (float*)(ws + (size_t)B_ * N_ * C_ * 4 + (size_t)B_ * M_ * S_ * 4);

    k_phase1<<<1024 + B_ * M_, 256, 0, stream>>>(feat, featT, pts, ctr, idx_ws);
    k_sums<<<B_ * M_ / 8, 256, 0, stream>>>(pts, ctr, featT, cfeat, idx_ws, bpart);
    k_output<<<1024, 256, 0, stream>>>(pts, ctr, featT, cfeat, alpha, beta,
                                       idx_ws, bpart, out);
}

// Round 9
// 47.335 us; speedup vs baseline: 4.7285x; 1.0300x over previous
//
#include <hip/hip_runtime.h>
#include <cstdint>
#include <cstddef>

#define B_ 4
#define N_ 16384
#define M_ 2048
#define C_ 64
#define S_ 32
#define J_ 67          // 3 + C
#define R2_ 0.04f
#define EPS_ 1e-5f

typedef float f32x4 __attribute__((ext_vector_type(4)));  // clang vector: valid
                                                          // for nontemporal builtins

// ---------------------------------------------------------------------------
// KA: fused independent phases.
//   blocks [0, 1024):    transpose features (B,C,N) -> featT (B,N,C)
//   blocks [1024, 9216): ball-query scan, one center per block (4 waves).
// Scan loads pts as float3 (global_load_dwordx3): 1 VMEM instr per point
// instead of 3 — 3x fewer L1/L2 transactions on the scan's hot path.
// ---------------------------------------------------------------------------
__global__ __launch_bounds__(256) void k_phase1(
        const float* __restrict__ feat, float* __restrict__ featT,
        const float* __restrict__ pts, const float* __restrict__ ctr,
        int* __restrict__ idx_ws) {
    __shared__ float tile[64][65];            // transpose tile (16.6 KB)
    int blk = blockIdx.x;
    int tid = threadIdx.x;

    if (blk < 1024) {
        // ---- transpose role ----
        int b  = blk >> 8;                    // N_/64 = 256 tiles per batch
        int n0 = (blk & 255) << 6;
        int r = tid >> 6, i = tid & 63;
        const float* fb = feat + (size_t)b * C_ * N_;
        #pragma unroll
        for (int cc = r; cc < 64; cc += 4)
            tile[cc][i] = fb[(size_t)cc * N_ + n0 + i];     // coalesced read
        __syncthreads();
        float* ftb = featT + (size_t)b * N_ * C_;
        #pragma unroll
        for (int nn = r; nn < 64; nn += 4)
            ftb[(size_t)(n0 + nn) * C_ + i] = tile[i][nn];  // coalesced write
        return;
    }

    // ---- ball-query scan role: one center per block, 4 waves ----
    __shared__ int wcnt[4];                   // per-wave in-chunk count (round)
    __shared__ int widx[4][S_];               // per-wave first-32 chunk indices
    __shared__ int result[S_];                // combined first-32 (ascending)
    int w    = tid >> 6;
    int lane = tid & 63;
    int bm   = blk - 1024;                    // 0..8191
    int b    = bm >> 11;                      // M_ = 2048
    const float3* pb3 = (const float3*)(pts + (size_t)b * N_ * 3);
    float cx = ctr[(size_t)bm * 3 + 0];
    float cy = ctr[(size_t)bm * 3 + 1];
    float cz = ctr[(size_t)bm * 3 + 2];

    float3 cur[4], nxtv[4];
    #pragma unroll
    for (int r = 0; r < 4; r++)               // round 0 chunk loads (dwordx3)
        cur[r] = pb3[w * 256 + r * 64 + lane];
    int total = 0;
    for (int base = 0; base < N_; base += 1024) {
        int nb = base + 1024;
        if (nb < N_) {
            #pragma unroll
            for (int r = 0; r < 4; r++)       // prefetch next round's chunk
                nxtv[r] = pb3[nb + w * 256 + r * 64 + lane];
        }
        int cbase = base + w * 256;
        int cnt = 0;                          // within-chunk count
        #pragma unroll
        for (int r = 0; r < 4; r++) {
            // bit-exact vs numpy: no FMA contraction, (x^2 + y^2) + z^2 order
            float dx = __fsub_rn(cx, cur[r].x);
            float dy = __fsub_rn(cy, cur[r].y);
            float dz = __fsub_rn(cz, cur[r].z);
            float d2 = __fadd_rn(__fadd_rn(__fmul_rn(dx, dx), __fmul_rn(dy, dy)),
                                 __fmul_rn(dz, dz));
            bool in = d2 < R2_;               // MIN_RADIUS=0: lower bound always true
            unsigned long long mk = __ballot(in);
            int rank = __popcll(mk & ((1ull << lane) - 1ull));
            int pos = cnt + rank;
            if (in && pos < S_) widx[w][pos] = cbase + r * 64 + lane;
            cnt += __popcll(mk);
        }
        if (lane == 0) wcnt[w] = cnt;
        __syncthreads();                      // wcnt/widx visible to all
        int c0 = wcnt[0], c1 = wcnt[1], c2 = wcnt[2], c3 = wcnt[3];
        int offw = total + ((w > 0) ? c0 : 0) + ((w > 1) ? c1 : 0) + ((w > 2) ? c2 : 0);
        int cw = wcnt[w] < S_ ? wcnt[w] : S_;
        if (lane < cw) {                      // concat wave segments, chunk order
            int dst = offw + lane;
            if (dst < S_) result[dst] = widx[w][lane];
        }
        __syncthreads();                      // result stable; widx reusable
        total += c0 + c1 + c2 + c3;
        if (total >= S_ || nb >= N_) break;   // block-uniform
        #pragma unroll
        for (int r = 0; r < 4; r++) cur[r] = nxtv[r];
    }
    int cfound = total < S_ ? total : S_;
    if (tid < S_) {
        int first = (cfound > 0) ? result[0] : 0;       // empty ball -> zeros
        int v = (tid < cfound) ? result[tid] : first;
        idx_ws[(size_t)bm * S_ + tid] = v;              // padded idx (ref semantics)
    }
}

// ---------------------------------------------------------------------------
// KB: per-center partial sums of centered values -> ONE partial per block
// (8 centers/block, 1024 blocks). Reassociated — only feeds the scalar std.
// ---------------------------------------------------------------------------
__global__ __launch_bounds__(256) void k_sums(
        const float* __restrict__ pts, const float* __restrict__ ctr,
        const float* __restrict__ featT, const float* __restrict__ cfeat,
        const int* __restrict__ idx_ws, float* __restrict__ bpart) {
    __shared__ float pp1[8], pp2[8];
    int w    = threadIdx.x >> 6;
    int lane = threadIdx.x & 63;
    #pragma unroll
    for (int cc = 0; cc < 2; cc++) {
        int ci = w * 2 + cc;
        int bm = blockIdx.x * 8 + ci;
        int b  = bm >> 11;
        const float3* pb3 = (const float3*)(pts + (size_t)b * N_ * 3);
        const float* ftb = featT + (size_t)b * N_ * C_;
        int id = idx_ws[(size_t)bm * S_ + (lane & 31)];
        float cf = cfeat[(size_t)bm * C_ + lane];
        float cx = ctr[(size_t)bm * 3 + 0];
        float cy = ctr[(size_t)bm * 3 + 1];
        float cz = ctr[(size_t)bm * 3 + 2];

        float s1 = 0.f, s2 = 0.f;
        float v[S_];
        #pragma unroll
        for (int s = 0; s < S_; s++) {        // 32 independent coalesced row loads
            int p = __shfl(id, s);
            v[s] = ftb[(size_t)p * C_ + lane];
        }
        #pragma unroll
        for (int s = 0; s < S_; s++) { float d = v[s] - cf; s1 += d; s2 += d * d; }
        float3 q = pb3[id];                   // one dwordx3 gather per lane
        float cj = (lane < 32) ? cx : cy;     // xyz spread across half-waves
        float pv = (lane < 32) ? q.x : q.y;
        float d0 = pv - cj; s1 += d0; s2 += d0 * d0;
        if (lane < 32) { float dz = q.z - cz; s1 += dz; s2 += dz * dz; }
        #pragma unroll
        for (int off = 32; off > 0; off >>= 1) {
            s1 += __shfl_down(s1, off);
            s2 += __shfl_down(s2, off);
        }
        if (lane == 0) { pp1[ci] = s1; pp2[ci] = s2; }
    }
    __syncthreads();
    if (threadIdx.x == 0) {                   // fixed-order block combine
        float a1 = 0.f, a2 = 0.f;
        #pragma unroll
        for (int i = 0; i < 8; i++) { a1 += pp1[i]; a2 += pp2[i]; }
        bpart[blockIdx.x * 2 + 0] = a1;
        bpart[blockIdx.x * 2 + 1] = a2;
    }
}

// ---------------------------------------------------------------------------
// K3: inline per-batch std reduce + output (B,67,M,S), f32x4 NONTEMPORAL
// stores (out is write-once: don't evict the L2-resident featT gather rows).
// 1024 blocks: thread = (mi = tid>>5, cg = (tid>>3)&3, sq = tid&7).
// ---------------------------------------------------------------------------
__global__ __launch_bounds__(256) void k_output(
        const float* __restrict__ pts, const float* __restrict__ ctr,
        const float* __restrict__ featT, const float* __restrict__ cfeat,
        const float* __restrict__ alpha, const float* __restrict__ beta,
        const int* __restrict__ idx_ws, const float* __restrict__ bpart,
        float* __restrict__ out) {
    __shared__ float r1[256], r2[256];
    int blk = blockIdx.x, tid = threadIdx.x;
    int batch = blk >> 8;                     // 256 blocks per batch

    // --- per-batch std (deterministic tree over 256 block-partials) ---
    const float* bp = bpart + (size_t)batch * 256 * 2;
    r1[tid] = bp[tid * 2 + 0];
    r2[tid] = bp[tid * 2 + 1];
    __syncthreads();
    for (int off = 128; off > 0; off >>= 1) {
        if (tid < off) { r1[tid] += r1[tid + off]; r2[tid] += r2[tid + off]; }
        __syncthreads();
    }
    float sum = r1[0], sumsq = r2[0];
    const float n = (float)(M_ * S_ * J_);            // 4390912 < 2^24, exact
    float mean = sum / n;
    float var  = (sumsq - sum * mean) / (n - 1.f);    // ddof = 1
    float inv  = 1.f / (sqrtf(var) + EPS_);

    // --- output: 8 m's per block, channels split across 4 thread-groups ---
    int mi = tid >> 5;                        // 0..7
    int cg = (tid >> 3) & 3;                  // channel group: 16 channels each
    int sq = tid & 7;                         // s-quad
    int m  = (blk & 255) * 8 + mi;
    int s0 = sq * 4;
    size_t bm = (size_t)batch * M_ + m;
    int4 pidx = *(const int4*)(idx_ws + bm * S_ + s0);
    size_t obase = ((size_t)batch * J_ * M_ + m) * (size_t)S_ + s0;

    if (cg == 0) {                            // xyz rows: dwordx3 gathers
        const float3* pb3 = (const float3*)(pts + (size_t)batch * N_ * 3);
        float3 q0 = pb3[pidx.x], q1 = pb3[pidx.y], q2 = pb3[pidx.z], q3 = pb3[pidx.w];
        float3 cj3;
        cj3.x = ctr[bm * 3 + 0]; cj3.y = ctr[bm * 3 + 1]; cj3.z = ctr[bm * 3 + 2];
        {
            float a = alpha[0] * inv, bt = beta[0];
            f32x4 o = { a * (q0.x - cj3.x) + bt, a * (q1.x - cj3.x) + bt,
                        a * (q2.x - cj3.x) + bt, a * (q3.x - cj3.x) + bt };
            __builtin_nontemporal_store(o, (f32x4*)(out + obase + (size_t)0 * (M_ * S_)));
        }
        {
            float a = alpha[1] * inv, bt = beta[1];
            f32x4 o = { a * (q0.y - cj3.y) + bt, a * (q1.y - cj3.y) + bt,
                        a * (q2.y - cj3.y) + bt, a * (q3.y - cj3.y) + bt };
            __builtin_nontemporal_store(o, (f32x4*)(out + obase + (size_t)1 * (M_ * S_)));
        }
        {
            float a = alpha[2] * inv, bt = beta[2];
            f32x4 o = { a * (q0.z - cj3.z) + bt, a * (q1.z - cj3.z) + bt,
                        a * (q2.z - cj3.z) + bt, a * (q3.z - cj3.z) + bt };
            __builtin_nontemporal_store(o, (f32x4*)(out + obase + (size_t)2 * (M_ * S_)));
        }
    }
    const float4* f0 = (const float4*)(featT + ((size_t)batch * N_ + pidx.x) * C_);
    const float4* f1 = (const float4*)(featT + ((size_t)batch * N_ + pidx.y) * C_);
    const float4* f2 = (const float4*)(featT + ((size_t)batch * N_ + pidx.z) * C_);
    const float4* f3 = (const float4*)(featT + ((size_t)batch * N_ + pidx.w) * C_);
    const float4* cf = (const float4*)(cfeat + bm * C_);
    #pragma unroll
    for (int cq = cg * 4; cq < cg * 4 + 4; cq++) {
        float4 v0 = f0[cq], v1 = f1[cq], v2 = f2[cq], v3 = f3[cq], c = cf[cq];
        int j = 3 + cq * 4;
        float a0 = alpha[j + 0] * inv, b0 = beta[j + 0];
        float a1 = alpha[j + 1] * inv, b1 = beta[j + 1];
        float a2 = alpha[j + 2] * inv, b2 = beta[j + 2];
        float a3 = alpha[j + 3] * inv, b3 = beta[j + 3];
        f32x4 o0, o1, o2, o3;                 // transpose 4x4 block in regs
        o0.x = a0 * (v0.x - c.x) + b0; o0.y = a0 * (v1.x - c.x) + b0;
        o0.z = a0 * (v2.x - c.x) + b0; o0.w = a0 * (v3.x - c.x) + b0;
        o1.x = a1 * (v0.y - c.y) + b1; o1.y = a1 * (v1.y - c.y) + b1;
        o1.z = a1 * (v2.y - c.y) + b1; o1.w = a1 * (v3.y - c.y) + b1;
        o2.x = a2 * (v0.z - c.z) + b2; o2.y = a2 * (v1.z - c.z) + b2;
        o2.z = a2 * (v2.z - c.z) + b2; o2.w = a2 * (v3.z - c.z) + b2;
        o3.x = a3 * (v0.w - c.w) + b3; o3.y = a3 * (v1.w - c.w) + b3;
        o3.z = a3 * (v2.w - c.w) + b3; o3.w = a3 * (v3.w - c.w) + b3;
        __builtin_nontemporal_store(o0, (f32x4*)(out + obase + (size_t)(j + 0) * (M_ * S_)));
        __builtin_nontemporal_store(o1, (f32x4*)(out + obase + (size_t)(j + 1) * (M_ * S_)));
        __builtin_nontemporal_store(o2, (f32x4*)(out + obase + (size_t)(j + 2) * (M_ * S_)));
        __builtin_nontemporal_store(o3, (f32x4*)(out + obase + (size_t)(j + 3) * (M_ * S_)));
    }
}

// ---------------------------------------------------------------------------
extern "C" void kernel_launch(void* const* d_in, const int* in_sizes, int n_in,
                              void* d_out, int out_size, void* d_ws, size_t ws_size,
                              hipStream_t stream) {
    const float* pts   = (const float*)d_in[0];   // (B,N,3)
    const float* ctr   = (const float*)d_in[1];   // (B,M,3)
    const float* cfeat = (const float*)d_in[2];   // (B,M,C)
    const float* feat  = (const float*)d_in[3];   // (B,C,N)
    const float* alpha = (const float*)d_in[4];   // (67)
    const float* beta  = (const float*)d_in[5];   // (67)
    float* out = (float*)d_out;

    // ws: featT 16 MB | idx 1 MB | bpart 8 KB
    char* ws = (char*)d_ws;
    float* featT = (float*)ws;
    int*   idx_ws = (int*)(ws + (size_t)B_ * N_ * C_ * 4);
    float* bpart = (float*)(ws + (size_t)B_ * N_ * C_ * 4 + (size_t)B_ * M_ * S_ * 4);

    k_phase1<<<1024 + B_ * M_, 256, 0, stream>>>(feat, featT, pts, ctr, idx_ws);
    k_sums<<<B_ * M_ / 8, 256, 0, stream>>>(pts, ctr, featT, cfeat, idx_ws, bpart);
    k_output<<<1024, 256, 0, stream>>>(pts, ctr, featT, cfeat, alpha, beta,
                                       idx_ws, bpart, out);
}